// Round 5
// baseline (209.976 us; speedup 1.0000x reference)
//
#include <hip/hip_runtime.h>
#include <hip/hip_cooperative_groups.h>

namespace cg = cooperative_groups;

#define BATCH 2048
#define DIM   256

typedef _Float16 half8 __attribute__((ext_vector_type(8)));  // 8 x f16 (4 VGPR)
typedef __attribute__((ext_vector_type(4))) float f32x4;

// Packed-weight tile table (layers 1..5), feature-major A-fragments:
// (FI,FO): (32,64) (64,128) (128,64) (64,32) (32,16)
// tiles = KT*NT = 4, 16, 16, 4, 1 -> bases 0, 4, 20, 36, 40
#define NTILES 41
#define TILE_HALVES 512        // 64 lanes * 8 f16 = 1 KB per tile
#define JOBS (NTILES * 64)     // 2624 half8 units per d

// params LDS (float offsets); all bias reads are 16B-aligned f32x4
#define P_W0 0
#define P_B0 32
#define P_W6 64
#define P_B1 80
#define P_B2 144
#define P_B3 272
#define P_B4 336
#define P_B5 368
#define P_B6 384
#define P_TOT 385

// Fragment state: NAMED members only (no arrays!). R1 lesson: half8[2][4]
// passed as pointer-to-array defeated SROA -> 240 MB of scratch traffic.
struct Frag { half8 k0, k1, k2, k3; };

__device__ __forceinline__ half8 relu_pack(f32x4 e, f32x4 o) {
  half8 r;
#pragma unroll
  for (int j = 0; j < 4; ++j) {
    r[j]     = (_Float16)fmaxf(e[j], 0.0f);
    r[4 + j] = (_Float16)fmaxf(o[j], 0.0f);
  }
  return r;
}

// Dependent MFMA chain over the K tiles of one 16-row output tile.
template <int KT>
__device__ __forceinline__ f32x4 chain(const _Float16* __restrict__ tb,
                                       const Frag& a, f32x4 c) {
  c = __builtin_amdgcn_mfma_f32_16x16x32_f16(*(const half8*)tb, a.k0, c, 0, 0, 0);
  if constexpr (KT > 1)
    c = __builtin_amdgcn_mfma_f32_16x16x32_f16(*(const half8*)(tb + TILE_HALVES),
                                               a.k1, c, 0, 0, 0);
  if constexpr (KT > 2) {
    c = __builtin_amdgcn_mfma_f32_16x16x32_f16(
        *(const half8*)(tb + 2 * TILE_HALVES), a.k2, c, 0, 0, 0);
    c = __builtin_amdgcn_mfma_f32_16x16x32_f16(
        *(const half8*)(tb + 3 * TILE_HALVES), a.k3, c, 0, 0, 0);
  }
  return c;
}

// One 32-feature output pair (mt even/odd) for FOUR batch row-tiles.
// Bias folded into the MFMA C operand. 8 independent MFMA chains; the two
// weight-tile streams (tb0/tb1) are each loaded once and reused 4x (CSE).
template <int KT, int TBASE, int PB>
__device__ __forceinline__ void ntp_pair(
    const _Float16* __restrict__ packs, const float* __restrict__ pl, int lane,
    int q, const Frag& a0, const Frag& a1, const Frag& a2, const Frag& a3,
    half8& r0, half8& r1, half8& r2, half8& r3) {
  const f32x4 bias0 = *(const f32x4*)(pl + PB + (q << 2));
  const f32x4 bias1 = *(const f32x4*)(pl + PB + 16 + (q << 2));
  const _Float16* tb0 = packs + (size_t)TBASE * TILE_HALVES + lane * 8;
  const _Float16* tb1 = tb0 + (size_t)KT * TILE_HALVES;
  const f32x4 c00 = chain<KT>(tb0, a0, bias0);
  const f32x4 c01 = chain<KT>(tb0, a1, bias0);
  const f32x4 c02 = chain<KT>(tb0, a2, bias0);
  const f32x4 c03 = chain<KT>(tb0, a3, bias0);
  const f32x4 c10 = chain<KT>(tb1, a0, bias1);
  const f32x4 c11 = chain<KT>(tb1, a1, bias1);
  const f32x4 c12 = chain<KT>(tb1, a2, bias1);
  const f32x4 c13 = chain<KT>(tb1, a3, bias1);
  // C-output at lane (m,q) = feats {32*ntp + 4q+j (even mt), +16 (odd mt)},
  // batch col m == exactly the B-fragment this lane feeds to the next layer
  // under the fixed K-permutation fi(q,j)=16*(j>>2)+4q+(j&3) baked into the
  // weight pack. Transition = in-register ReLU + f16 cvt. No LDS, no shuffle.
  r0 = relu_pack(c00, c10);
  r1 = relu_pack(c01, c11);
  r2 = relu_pack(c02, c12);
  r3 = relu_pack(c03, c13);
}

template <int FI, int FO, int LBASE, int PBIAS>
__device__ __forceinline__ void layerX(
    const _Float16* __restrict__ packs, const float* __restrict__ pl, int lane,
    int q, const Frag& a0, const Frag& a1, const Frag& a2, const Frag& a3,
    Frag& o0, Frag& o1, Frag& o2, Frag& o3) {
  constexpr int KT = FI / 32, NTP = FO / 32;
  ntp_pair<KT, LBASE + 0 * 2 * KT, PBIAS + 0 * 32>(
      packs, pl, lane, q, a0, a1, a2, a3, o0.k0, o1.k0, o2.k0, o3.k0);
  if constexpr (NTP > 1)
    ntp_pair<KT, LBASE + 1 * 2 * KT, PBIAS + 1 * 32>(
        packs, pl, lane, q, a0, a1, a2, a3, o0.k1, o1.k1, o2.k1, o3.k1);
  if constexpr (NTP > 2) {
    ntp_pair<KT, LBASE + 2 * 2 * KT, PBIAS + 2 * 32>(
        packs, pl, lane, q, a0, a1, a2, a3, o0.k2, o1.k2, o2.k2, o3.k2);
    ntp_pair<KT, LBASE + 3 * 2 * KT, PBIAS + 3 * 32>(
        packs, pl, lane, q, a0, a1, a2, a3, o0.k3, o1.k3, o2.k3, o3.k3);
  }
}

// SINGLE cooperative kernel. grid 256 (one block per d, 1 block/CU).
// Phase 1: gather W1..W5[d] into LDS A-frag order ONCE per d + x column +
// params. Phase 2: 4 iterations of 8 waves x 4 row-tiles x 16 rows = 2048
// rows, fully in-register between layers. Then grid.sync() + distributed
// cross-d tail reduction (block g reduces outputs 8g..8g+7) -- no separate
// reduce kernel, no atomics, deterministic order.
// LDS = 41 KB packs + 8 KB xs + 1.5 KB pl + 2 KB red ~= 53 KB. One barrier
// in the MLP part; the all-memory asm fence of R2/R3 is replaced by
// opaque-offset pointers on packs/pl only, so xs/L0 head and L6 store tail
// can pipeline across iterations while weight tiles still can't be hoisted
// (spill protection).
__global__ __launch_bounds__(512, 2) void mlp_fused(
    const float* __restrict__ x,
    const float* __restrict__ W0, const float* __restrict__ b0,
    const float* __restrict__ W1, const float* __restrict__ b1,
    const float* __restrict__ W2, const float* __restrict__ b2,
    const float* __restrict__ W3, const float* __restrict__ b3,
    const float* __restrict__ W4, const float* __restrict__ b4,
    const float* __restrict__ W5, const float* __restrict__ b5,
    const float* __restrict__ W6, const float* __restrict__ b6,
    float* __restrict__ partial, float* __restrict__ out) {
  const int t = threadIdx.x;
  const int lane = t & 63;
  const int wave = t >> 6;
  const int m = lane & 15, q = lane >> 4;
  const int d = blockIdx.x;

  __shared__ __align__(16) _Float16 packs[NTILES * TILE_HALVES];  // 41 KB
  __shared__ __align__(16) float xs[2048];                        // 8 KB
  __shared__ __align__(16) float pl[P_TOT];
  __shared__ __align__(16) float red[64][8];                      // 2 KB

  // ---- phase 1a: stage x column (stride-1KB gather, issued all at once) ----
  for (int i = t; i < 2048; i += 512)
    xs[i] = x[(size_t)i * DIM + d];

  // ---- phase 1b: gather W1..W5[d] into A-fragment order (f16 rne) ----
  // A-frag: lane (jm,jq) elem j = W[32*kt + 16*(j>>2) + 4*jq + (j&3)][16*mt+jm]
  for (int job = t; job < JOBS; job += 512) {
    const int tile = job >> 6, jl = job & 63;
    const int jm = jl & 15, jq = jl >> 4;
    const float* W; int FI, FO, lt;
    if (tile < 4)       { W = W1; FI = 32;  FO = 64;  lt = tile; }
    else if (tile < 20) { W = W2; FI = 64;  FO = 128; lt = tile - 4; }
    else if (tile < 36) { W = W3; FI = 128; FO = 64;  lt = tile - 20; }
    else if (tile < 40) { W = W4; FI = 64;  FO = 32;  lt = tile - 36; }
    else                { W = W5; FI = 32;  FO = 16;  lt = 0; }
    const int KT = FI >> 5;
    const int mt = lt / KT, kt = lt - mt * KT;
    const float* Wp = W + (size_t)d * FI * FO + (size_t)kt * 32 * FO +
                      mt * 16 + jm;
    half8 hi;
#pragma unroll
    for (int j = 0; j < 8; ++j) {
      const int fi = 16 * (j >> 2) + 4 * jq + (j & 3);
      hi[j] = (_Float16)Wp[(size_t)fi * FO];
    }
    *(half8*)(packs + (size_t)tile * TILE_HALVES + jl * 8) = hi;
  }
  // ---- phase 1c: stage small params (W0,b0,W6,b1..b5,b6) as f32 ----
  for (int i = t; i < P_TOT; i += 512) {
    float v;
    if (i < 32)       v = W0[d * 32 + i];
    else if (i < 64)  v = b0[d * 32 + i - 32];
    else if (i < 80)  v = W6[d * 16 + i - 64];
    else if (i < 144) v = b1[d * 64 + i - 80];
    else if (i < 272) v = b2[d * 128 + i - 144];
    else if (i < 336) v = b3[d * 64 + i - 272];
    else if (i < 368) v = b4[d * 32 + i - 336];
    else if (i < 384) v = b5[d * 16 + i - 368];
    else              v = b6[d];
    pl[i] = v;
  }

  __syncthreads();   // pack ready

  Frag pA0, pA1, pA2, pA3, pB0, pB1, pB2, pB3;  // ping-pong, named members

  int opq = 0;  // opaque 0: blocks LICM of tile/bias loads, allows xs/L0/L6
                // cross-iteration pipelining (R2/R3 used a full mem fence).
  for (int it = 0; it < 4; ++it) {
    asm volatile("" : "+v"(opq));
    const _Float16* pk = packs + opq;
    const float* plq = pl + opq;

    const int row0 = it * 512 + wave * 64;

    // L0/L6 params (permuted order for L0 so L1's B-frag is direct).
    const f32x4 w0a = *(const f32x4*)(plq + P_W0 + 4 * q);
    const f32x4 w0b = *(const f32x4*)(plq + P_W0 + 16 + 4 * q);
    const f32x4 b0a = *(const f32x4*)(plq + P_B0 + 4 * q);
    const f32x4 b0b = *(const f32x4*)(plq + P_B0 + 16 + 4 * q);

    // L0: 1 -> 32 in VALU, directly in permuted B-frag order.
    {
      const int xb = row0 + m;
      const float xv0 = xs[xb];
      const float xv1 = xs[xb + 16];
      const float xv2 = xs[xb + 32];
      const float xv3 = xs[xb + 48];
      half8 h0, h1, h2, h3;
#pragma unroll
      for (int j = 0; j < 4; ++j) {
        h0[j]     = (_Float16)fmaxf(fmaf(xv0, w0a[j], b0a[j]), 0.0f);
        h0[4 + j] = (_Float16)fmaxf(fmaf(xv0, w0b[j], b0b[j]), 0.0f);
        h1[j]     = (_Float16)fmaxf(fmaf(xv1, w0a[j], b0a[j]), 0.0f);
        h1[4 + j] = (_Float16)fmaxf(fmaf(xv1, w0b[j], b0b[j]), 0.0f);
        h2[j]     = (_Float16)fmaxf(fmaf(xv2, w0a[j], b0a[j]), 0.0f);
        h2[4 + j] = (_Float16)fmaxf(fmaf(xv2, w0b[j], b0b[j]), 0.0f);
        h3[j]     = (_Float16)fmaxf(fmaf(xv3, w0a[j], b0a[j]), 0.0f);
        h3[4 + j] = (_Float16)fmaxf(fmaf(xv3, w0b[j], b0b[j]), 0.0f);
      }
      pA0.k0 = h0;
      pA1.k0 = h1;
      pA2.k0 = h2;
      pA3.k0 = h3;
    }

    layerX<32, 64, 0, P_B1>(pk, plq, lane, q,                    // L1
                            pA0, pA1, pA2, pA3, pB0, pB1, pB2, pB3);
    layerX<64, 128, 4, P_B2>(pk, plq, lane, q,                   // L2
                             pB0, pB1, pB2, pB3, pA0, pA1, pA2, pA3);
    layerX<128, 64, 20, P_B3>(pk, plq, lane, q,                  // L3
                              pA0, pA1, pA2, pA3, pB0, pB1, pB2, pB3);
    layerX<64, 32, 36, P_B4>(pk, plq, lane, q,                   // L4
                             pB0, pB1, pB2, pB3, pA0, pA1, pA2, pA3);

    // L5 (32->16, single tile) + L6 (16->1) fully in-register.
    const f32x4 bias5 = *(const f32x4*)(plq + P_B5 + 4 * q);
    const f32x4 w6v = *(const f32x4*)(plq + P_W6 + 4 * q);
    const float bias6 = plq[P_B6];
    const half8 wf5 = *(const half8*)(pk + (size_t)40 * TILE_HALVES + lane * 8);

    const f32x4 a50 = __builtin_amdgcn_mfma_f32_16x16x32_f16(
        wf5, pA0.k0, bias5, 0, 0, 0);
    const f32x4 a51 = __builtin_amdgcn_mfma_f32_16x16x32_f16(
        wf5, pA1.k0, bias5, 0, 0, 0);
    const f32x4 a52 = __builtin_amdgcn_mfma_f32_16x16x32_f16(
        wf5, pA2.k0, bias5, 0, 0, 0);
    const f32x4 a53 = __builtin_amdgcn_mfma_f32_16x16x32_f16(
        wf5, pA3.k0, bias5, 0, 0, 0);
    // lane (m,q) holds H5[4q+r][batch m]; dot with W6 then reduce over q.
    float v0 = 0.0f, v1 = 0.0f, v2 = 0.0f, v3 = 0.0f;
#pragma unroll
    for (int r = 0; r < 4; ++r) {
      v0 += fmaxf(a50[r], 0.0f) * w6v[r];
      v1 += fmaxf(a51[r], 0.0f) * w6v[r];
      v2 += fmaxf(a52[r], 0.0f) * w6v[r];
      v3 += fmaxf(a53[r], 0.0f) * w6v[r];
    }
    v0 += __shfl_xor(v0, 16);
    v0 += __shfl_xor(v0, 32);
    v1 += __shfl_xor(v1, 16);
    v1 += __shfl_xor(v1, 32);
    v2 += __shfl_xor(v2, 16);
    v2 += __shfl_xor(v2, 32);
    v3 += __shfl_xor(v3, 16);
    v3 += __shfl_xor(v3, 32);
    if (q == 0) {
      partial[(size_t)d * BATCH + row0 + m]      = v0 + bias6;
      partial[(size_t)d * BATCH + row0 + 16 + m] = v1 + bias6;
      partial[(size_t)d * BATCH + row0 + 32 + m] = v2 + bias6;
      partial[(size_t)d * BATCH + row0 + 48 + m] = v3 + bias6;
    }
  }

  // ---- tail: grid-wide sync, then block g reduces outputs 8g..8g+7 over
  // all 256 d. Deterministic order, no atomics. __threadfence for cross-XCD
  // visibility of partial (per-XCD L2s are not coherent).
  __threadfence();
  cg::this_grid().sync();

  const int dg = t >> 3, bl = t & 7;          // 64 d-groups x 8 outputs
  const int bout = d * 8 + bl;                // block g == d covers 8 outputs
  float s = 0.0f;
#pragma unroll
  for (int k = 0; k < 4; ++k)
    s += partial[(size_t)(dg * 4 + k) * BATCH + bout];
  red[dg][bl] = s;
  __syncthreads();
  if (t < 8) {
    float acc = 0.0f;
    for (int j = 0; j < 64; ++j) acc += red[j][t];
    out[d * 8 + t] = acc;
  }
}

extern "C" void kernel_launch(void* const* d_in, const int* in_sizes, int n_in,
                              void* d_out, int out_size, void* d_ws, size_t ws_size,
                              hipStream_t stream) {
  const float* x = (const float*)d_in[0];
  const float* W0 = (const float*)d_in[1];
  const float* B0 = (const float*)d_in[2];
  const float* W1 = (const float*)d_in[3];
  const float* B1 = (const float*)d_in[4];
  const float* W2 = (const float*)d_in[5];
  const float* B2 = (const float*)d_in[6];
  const float* W3 = (const float*)d_in[7];
  const float* B3 = (const float*)d_in[8];
  const float* W4 = (const float*)d_in[9];
  const float* B4 = (const float*)d_in[10];
  const float* W5 = (const float*)d_in[11];
  const float* B5 = (const float*)d_in[12];
  const float* W6 = (const float*)d_in[13];
  const float* B6 = (const float*)d_in[14];
  float* partial = (float*)d_ws;  // 2 MB
  float* out = (float*)d_out;

  void* args[] = {&x,  &W0, &B0, &W1, &B1, &W2, &B2, &W3, &B3,
                  &W4, &B4, &W5, &B5, &W6, &B6, &partial, &out};

  hipLaunchCooperativeKernel((const void*)mlp_fused, dim3(DIM), dim3(512),
                             args, 0, stream);
}

// Round 6
// 132.644 us; speedup vs baseline: 1.5830x; 1.5830x over previous
//
#include <hip/hip_runtime.h>

#define BATCH 2048
#define DIM   256

typedef _Float16 half8 __attribute__((ext_vector_type(8)));  // 8 x f16 (4 VGPR)
typedef __attribute__((ext_vector_type(4))) float f32x4;

// Packed-weight tile table (layers 1..5), feature-major A-fragments:
// (FI,FO): (32,64) (64,128) (128,64) (64,32) (32,16)
// tiles = KT*NT = 4, 16, 16, 4, 1 -> bases 0, 4, 20, 36, 40
#define NTILES 41
#define TILE_HALVES 512        // 64 lanes * 8 f16 = 1 KB per tile

// params LDS (float offsets); all bias reads are 16B-aligned f32x4
#define P_W0 0
#define P_B0 32
#define P_W6 64
#define P_B1 80
#define P_B2 144
#define P_B3 272
#define P_B4 336
#define P_B5 368
#define P_B6 384
#define P_TOT 385

// Fragment state: NAMED members only (no arrays!). R1 lesson: half8[2][4]
// passed as pointer-to-array defeated SROA -> 240 MB of scratch traffic.
struct Frag { half8 k0, k1, k2, k3; };

__device__ __forceinline__ half8 relu_pack(f32x4 e, f32x4 o) {
  half8 r;
#pragma unroll
  for (int j = 0; j < 4; ++j) {
    r[j]     = (_Float16)fmaxf(e[j], 0.0f);
    r[4 + j] = (_Float16)fmaxf(o[j], 0.0f);
  }
  return r;
}

// Dependent MFMA chain over the K tiles of one 16-row output tile.
template <int KT>
__device__ __forceinline__ f32x4 chain(const _Float16* __restrict__ tb,
                                       const Frag& a, f32x4 c) {
  c = __builtin_amdgcn_mfma_f32_16x16x32_f16(*(const half8*)tb, a.k0, c, 0, 0, 0);
  if constexpr (KT > 1)
    c = __builtin_amdgcn_mfma_f32_16x16x32_f16(*(const half8*)(tb + TILE_HALVES),
                                               a.k1, c, 0, 0, 0);
  if constexpr (KT > 2) {
    c = __builtin_amdgcn_mfma_f32_16x16x32_f16(
        *(const half8*)(tb + 2 * TILE_HALVES), a.k2, c, 0, 0, 0);
    c = __builtin_amdgcn_mfma_f32_16x16x32_f16(
        *(const half8*)(tb + 3 * TILE_HALVES), a.k3, c, 0, 0, 0);
  }
  return c;
}

// One 32-feature output pair (mt even/odd) for FOUR batch row-tiles.
// Bias folded into the MFMA C operand. 8 independent MFMA chains; the two
// weight-tile streams (tb0/tb1) are each loaded once and reused 4x (CSE).
template <int KT, int TBASE, int PB>
__device__ __forceinline__ void ntp_pair(
    const _Float16* __restrict__ packs, const float* __restrict__ pl, int lane,
    int q, const Frag& a0, const Frag& a1, const Frag& a2, const Frag& a3,
    half8& r0, half8& r1, half8& r2, half8& r3) {
  const f32x4 bias0 = *(const f32x4*)(pl + PB + (q << 2));
  const f32x4 bias1 = *(const f32x4*)(pl + PB + 16 + (q << 2));
  const _Float16* tb0 = packs + (size_t)TBASE * TILE_HALVES + lane * 8;
  const _Float16* tb1 = tb0 + (size_t)KT * TILE_HALVES;
  const f32x4 c00 = chain<KT>(tb0, a0, bias0);
  const f32x4 c01 = chain<KT>(tb0, a1, bias0);
  const f32x4 c02 = chain<KT>(tb0, a2, bias0);
  const f32x4 c03 = chain<KT>(tb0, a3, bias0);
  const f32x4 c10 = chain<KT>(tb1, a0, bias1);
  const f32x4 c11 = chain<KT>(tb1, a1, bias1);
  const f32x4 c12 = chain<KT>(tb1, a2, bias1);
  const f32x4 c13 = chain<KT>(tb1, a3, bias1);
  // C-output at lane (m,q) = feats {32*ntp + 4q+j (even mt), +16 (odd mt)},
  // batch col m == exactly the B-fragment this lane feeds to the next layer
  // under the fixed K-permutation fi(q,j)=16*(j>>2)+4q+(j&3) baked into the
  // weight pack. Transition = in-register ReLU + f16 cvt. No LDS, no shuffle.
  r0 = relu_pack(c00, c10);
  r1 = relu_pack(c01, c11);
  r2 = relu_pack(c02, c12);
  r3 = relu_pack(c03, c13);
}

template <int FI, int FO, int LBASE, int PBIAS>
__device__ __forceinline__ void layerX(
    const _Float16* __restrict__ packs, const float* __restrict__ pl, int lane,
    int q, const Frag& a0, const Frag& a1, const Frag& a2, const Frag& a3,
    Frag& o0, Frag& o1, Frag& o2, Frag& o3) {
  constexpr int KT = FI / 32, NTP = FO / 32;
  ntp_pair<KT, LBASE + 0 * 2 * KT, PBIAS + 0 * 32>(
      packs, pl, lane, q, a0, a1, a2, a3, o0.k0, o1.k0, o2.k0, o3.k0);
  if constexpr (NTP > 1)
    ntp_pair<KT, LBASE + 1 * 2 * KT, PBIAS + 1 * 32>(
        packs, pl, lane, q, a0, a1, a2, a3, o0.k1, o1.k1, o2.k1, o3.k1);
  if constexpr (NTP > 2) {
    ntp_pair<KT, LBASE + 2 * 2 * KT, PBIAS + 2 * 32>(
        packs, pl, lane, q, a0, a1, a2, a3, o0.k2, o1.k2, o2.k2, o3.k2);
    ntp_pair<KT, LBASE + 3 * 2 * KT, PBIAS + 3 * 32>(
        packs, pl, lane, q, a0, a1, a2, a3, o0.k3, o1.k3, o2.k3, o3.k3);
  }
}

// grid (256 d, 2 batch-halves), 512 threads, 2 blocks/CU (R3 structure --
// best measured; R5's cooperative 1-block/CU variant regressed 1.6x).
// Phase 1: COALESCED gather (R5 change): each thread loads 8x float4
// (4 adjacent output columns x 8 fragment rows) and writes 4 contiguous
// packed half8 fragments -> 4x fewer L2 transactions than the scalar
// gather (R0-R4: 8 scalar stride-256B loads per fragment).
// Phase 2: 2 iterations of 8 waves x 4 row-tiles x 16 rows = 1024 rows,
// fully in-register between layers (identical to R3).
__global__ __launch_bounds__(512, 2) void mlp_fused(
    const float* __restrict__ x,
    const float* __restrict__ W0, const float* __restrict__ b0,
    const float* __restrict__ W1, const float* __restrict__ b1,
    const float* __restrict__ W2, const float* __restrict__ b2,
    const float* __restrict__ W3, const float* __restrict__ b3,
    const float* __restrict__ W4, const float* __restrict__ b4,
    const float* __restrict__ W5, const float* __restrict__ b5,
    const float* __restrict__ W6, const float* __restrict__ b6,
    float* __restrict__ partial) {
  const int t = threadIdx.x;
  const int lane = t & 63;
  const int wave = t >> 6;
  const int m = lane & 15, q = lane >> 4;
  const int d = blockIdx.x;
  const int halfb = blockIdx.y;

  __shared__ __align__(16) _Float16 packs[NTILES * TILE_HALVES];  // 41 KB
  __shared__ __align__(16) float xs[1024];                        // 4 KB
  __shared__ __align__(16) float pl[P_TOT];

  // ---- phase 1a: stage x column (stride-1KB gather, issued all at once) ----
  for (int i = t; i < 1024; i += 512)
    xs[i] = x[(size_t)(halfb * 1024 + i) * DIM + d];

  // ---- phase 1b: gather W1..W5[d] into A-fragment order (f16 rne) ----
  // Target (unchanged from R2-R4): packs[tile][jq*16+jm][j] =
  //   (f16) W[32*kt + 16*(j>>2) + 4*jq + (j&3)][16*mt + jm].
  // New job shape: (tile, jq, jm4) covers jm = 4*jm4 .. +3 via 8 coalesced
  // float4 loads (rows {0,1,2,3,16,17,18,19} + 32kt+4jq; cols 16mt+4jm4..+3)
  // and 4 contiguous ds_write_b128. Same elements, same rne cvt.
  for (int job = t; job < NTILES * 16; job += 512) {
    const int tile = job >> 4, sub = job & 15;
    const int jq = sub >> 2, jm4 = sub & 3;
    const float* W; int FI, FO, lt;
    if (tile < 4)       { W = W1; FI = 32;  FO = 64;  lt = tile; }
    else if (tile < 20) { W = W2; FI = 64;  FO = 128; lt = tile - 4; }
    else if (tile < 36) { W = W3; FI = 128; FO = 64;  lt = tile - 20; }
    else if (tile < 40) { W = W4; FI = 64;  FO = 32;  lt = tile - 36; }
    else                { W = W5; FI = 32;  FO = 16;  lt = 0; }
    const int KT = FI >> 5;
    const int mt = lt / KT, kt = lt - mt * KT;
    const float* Wp = W + (size_t)d * FI * FO +
                      (size_t)(kt * 32 + 4 * jq) * FO + mt * 16 + jm4 * 4;
    const f32x4 v0 = *(const f32x4*)(Wp + (size_t)0 * FO);
    const f32x4 v1 = *(const f32x4*)(Wp + (size_t)1 * FO);
    const f32x4 v2 = *(const f32x4*)(Wp + (size_t)2 * FO);
    const f32x4 v3 = *(const f32x4*)(Wp + (size_t)3 * FO);
    const f32x4 v4 = *(const f32x4*)(Wp + (size_t)16 * FO);
    const f32x4 v5 = *(const f32x4*)(Wp + (size_t)17 * FO);
    const f32x4 v6 = *(const f32x4*)(Wp + (size_t)18 * FO);
    const f32x4 v7 = *(const f32x4*)(Wp + (size_t)19 * FO);
    _Float16* pb =
        packs + (size_t)tile * TILE_HALVES + (size_t)(jq * 16 + jm4 * 4) * 8;
#pragma unroll
    for (int c = 0; c < 4; ++c) {
      half8 h;
      h[0] = (_Float16)v0[c];
      h[1] = (_Float16)v1[c];
      h[2] = (_Float16)v2[c];
      h[3] = (_Float16)v3[c];
      h[4] = (_Float16)v4[c];
      h[5] = (_Float16)v5[c];
      h[6] = (_Float16)v6[c];
      h[7] = (_Float16)v7[c];
      *(half8*)(pb + c * 8) = h;
    }
  }
  // ---- phase 1c: stage small params (W0,b0,W6,b1..b5,b6) as f32 ----
  for (int i = t; i < P_TOT; i += 512) {
    float v;
    if (i < 32)       v = W0[d * 32 + i];
    else if (i < 64)  v = b0[d * 32 + i - 32];
    else if (i < 80)  v = W6[d * 16 + i - 64];
    else if (i < 144) v = b1[d * 64 + i - 80];
    else if (i < 272) v = b2[d * 128 + i - 144];
    else if (i < 336) v = b3[d * 64 + i - 272];
    else if (i < 368) v = b4[d * 32 + i - 336];
    else if (i < 384) v = b5[d * 16 + i - 368];
    else              v = b6[d];
    pl[i] = v;
  }

  __syncthreads();   // the ONLY barrier

  Frag pA0, pA1, pA2, pA3, pB0, pB1, pB2, pB3;  // ping-pong, named members

  for (int it = 0; it < 2; ++it) {
    // Compiler fence: keep the (cheap, loop-invariant) LDS reads of weights
    // and biases IN the loop -- hoisting all 41 weight tiles would need
    // 164+ VGPRs and re-trigger spill.
    asm volatile("" ::: "memory");

    const int row0 = halfb * 1024 + it * 512 + wave * 64;

    // L0/L6 params (permuted order for L0 so L1's B-frag is direct).
    // Loaded per-iter (post-fence) so they die before the layer stack peaks.
    const f32x4 w0a = *(const f32x4*)(pl + P_W0 + 4 * q);
    const f32x4 w0b = *(const f32x4*)(pl + P_W0 + 16 + 4 * q);
    const f32x4 b0a = *(const f32x4*)(pl + P_B0 + 4 * q);
    const f32x4 b0b = *(const f32x4*)(pl + P_B0 + 16 + 4 * q);

    // L0: 1 -> 32 in VALU, directly in permuted B-frag order.
    {
      const int xb = it * 512 + wave * 64 + m;
      const float xv0 = xs[xb];
      const float xv1 = xs[xb + 16];
      const float xv2 = xs[xb + 32];
      const float xv3 = xs[xb + 48];
      half8 h0, h1, h2, h3;
#pragma unroll
      for (int j = 0; j < 4; ++j) {
        h0[j]     = (_Float16)fmaxf(fmaf(xv0, w0a[j], b0a[j]), 0.0f);
        h0[4 + j] = (_Float16)fmaxf(fmaf(xv0, w0b[j], b0b[j]), 0.0f);
        h1[j]     = (_Float16)fmaxf(fmaf(xv1, w0a[j], b0a[j]), 0.0f);
        h1[4 + j] = (_Float16)fmaxf(fmaf(xv1, w0b[j], b0b[j]), 0.0f);
        h2[j]     = (_Float16)fmaxf(fmaf(xv2, w0a[j], b0a[j]), 0.0f);
        h2[4 + j] = (_Float16)fmaxf(fmaf(xv2, w0b[j], b0b[j]), 0.0f);
        h3[j]     = (_Float16)fmaxf(fmaf(xv3, w0a[j], b0a[j]), 0.0f);
        h3[4 + j] = (_Float16)fmaxf(fmaf(xv3, w0b[j], b0b[j]), 0.0f);
      }
      pA0.k0 = h0;
      pA1.k0 = h1;
      pA2.k0 = h2;
      pA3.k0 = h3;
    }

    layerX<32, 64, 0, P_B1>(packs, pl, lane, q,                    // L1
                            pA0, pA1, pA2, pA3, pB0, pB1, pB2, pB3);
    layerX<64, 128, 4, P_B2>(packs, pl, lane, q,                   // L2
                             pB0, pB1, pB2, pB3, pA0, pA1, pA2, pA3);
    layerX<128, 64, 20, P_B3>(packs, pl, lane, q,                  // L3
                              pA0, pA1, pA2, pA3, pB0, pB1, pB2, pB3);
    layerX<64, 32, 36, P_B4>(packs, pl, lane, q,                   // L4
                             pB0, pB1, pB2, pB3, pA0, pA1, pA2, pA3);

    // L5 (32->16, single tile) + L6 (16->1) fully in-register.
    const f32x4 bias5 = *(const f32x4*)(pl + P_B5 + 4 * q);
    const f32x4 w6v = *(const f32x4*)(pl + P_W6 + 4 * q);
    const float bias6 = pl[P_B6];
    const half8 wf5 =
        *(const half8*)(packs + (size_t)40 * TILE_HALVES + lane * 8);

    const f32x4 a50 = __builtin_amdgcn_mfma_f32_16x16x32_f16(
        wf5, pA0.k0, bias5, 0, 0, 0);
    const f32x4 a51 = __builtin_amdgcn_mfma_f32_16x16x32_f16(
        wf5, pA1.k0, bias5, 0, 0, 0);
    const f32x4 a52 = __builtin_amdgcn_mfma_f32_16x16x32_f16(
        wf5, pA2.k0, bias5, 0, 0, 0);
    const f32x4 a53 = __builtin_amdgcn_mfma_f32_16x16x32_f16(
        wf5, pA3.k0, bias5, 0, 0, 0);
    // lane (m,q) holds H5[4q+r][batch m]; dot with W6 then reduce over q.
    float v0 = 0.0f, v1 = 0.0f, v2 = 0.0f, v3 = 0.0f;
#pragma unroll
    for (int r = 0; r < 4; ++r) {
      v0 += fmaxf(a50[r], 0.0f) * w6v[r];
      v1 += fmaxf(a51[r], 0.0f) * w6v[r];
      v2 += fmaxf(a52[r], 0.0f) * w6v[r];
      v3 += fmaxf(a53[r], 0.0f) * w6v[r];
    }
    v0 += __shfl_xor(v0, 16);
    v0 += __shfl_xor(v0, 32);
    v1 += __shfl_xor(v1, 16);
    v1 += __shfl_xor(v1, 32);
    v2 += __shfl_xor(v2, 16);
    v2 += __shfl_xor(v2, 32);
    v3 += __shfl_xor(v3, 16);
    v3 += __shfl_xor(v3, 32);
    if (q == 0) {
      partial[(size_t)d * BATCH + row0 + m]      = v0 + bias6;
      partial[(size_t)d * BATCH + row0 + 16 + m] = v1 + bias6;
      partial[(size_t)d * BATCH + row0 + 32 + m] = v2 + bias6;
      partial[(size_t)d * BATCH + row0 + 48 + m] = v3 + bias6;
    }
  }
}

__global__ __launch_bounds__(256) void reduce_kernel(
    const float* __restrict__ partial, float* __restrict__ out) {
  const int b = blockIdx.x * blockDim.x + threadIdx.x;
  float s = 0.0f;
#pragma unroll 8
  for (int d = 0; d < DIM; ++d) s += partial[(size_t)d * BATCH + b];
  out[b] = s;
}

extern "C" void kernel_launch(void* const* d_in, const int* in_sizes, int n_in,
                              void* d_out, int out_size, void* d_ws, size_t ws_size,
                              hipStream_t stream) {
  const float* x = (const float*)d_in[0];
  const float* W[7];
  const float* B[7];
  for (int l = 0; l < 7; ++l) {
    W[l] = (const float*)d_in[1 + 2 * l];
    B[l] = (const float*)d_in[2 + 2 * l];
  }
  float* partial = (float*)d_ws;  // 2 MB

  mlp_fused<<<dim3(DIM, 2), dim3(512), 0, stream>>>(
      x, W[0], B[0], W[1], B[1], W[2], B[2], W[3], B[3], W[4], B[4], W[5], B[5],
      W[6], B[6], partial);

  reduce_kernel<<<dim3(BATCH / 256), dim3(256), 0, stream>>>(partial,
                                                             (float*)d_out);
}

// Round 7
// 129.430 us; speedup vs baseline: 1.6223x; 1.0248x over previous
//
#include <hip/hip_runtime.h>

#define BATCH 2048
#define DIM   256

typedef _Float16 half8 __attribute__((ext_vector_type(8)));  // 8 x f16 (4 VGPR)
typedef __attribute__((ext_vector_type(4))) float f32x4;

// Packed-weight tile table (layers 1..5), feature-major A-fragments:
// (FI,FO): (32,64) (64,128) (128,64) (64,32) (32,16)
// tiles = KT*NT = 4, 16, 16, 4, 1 -> bases 0, 4, 20, 36, 40
#define NTILES 41
#define TILE_HALVES 512        // 64 lanes * 8 f16 = 1 KB per tile

// params LDS (float offsets); all bias reads are 16B-aligned f32x4
#define P_W0 0
#define P_B0 32
#define P_W6 64
#define P_B1 80
#define P_B2 144
#define P_B3 272
#define P_B4 336
#define P_B5 368
#define P_B6 384
#define P_TOT 385

// Fragment state: NAMED members only (no arrays!). R1 lesson: half8[2][4]
// passed as pointer-to-array defeated SROA -> 240 MB of scratch traffic.
struct Frag { half8 k0, k1, k2, k3; };

__device__ __forceinline__ half8 relu_pack(f32x4 e, f32x4 o) {
  half8 r;
#pragma unroll
  for (int j = 0; j < 4; ++j) {
    r[j]     = (_Float16)fmaxf(e[j], 0.0f);
    r[4 + j] = (_Float16)fmaxf(o[j], 0.0f);
  }
  return r;
}

// Dependent MFMA chain over the K tiles of one 16-row output tile.
template <int KT>
__device__ __forceinline__ f32x4 chain(const _Float16* __restrict__ tb,
                                       const Frag& a, f32x4 c) {
  c = __builtin_amdgcn_mfma_f32_16x16x32_f16(*(const half8*)tb, a.k0, c, 0, 0, 0);
  if constexpr (KT > 1)
    c = __builtin_amdgcn_mfma_f32_16x16x32_f16(*(const half8*)(tb + TILE_HALVES),
                                               a.k1, c, 0, 0, 0);
  if constexpr (KT > 2) {
    c = __builtin_amdgcn_mfma_f32_16x16x32_f16(
        *(const half8*)(tb + 2 * TILE_HALVES), a.k2, c, 0, 0, 0);
    c = __builtin_amdgcn_mfma_f32_16x16x32_f16(
        *(const half8*)(tb + 3 * TILE_HALVES), a.k3, c, 0, 0, 0);
  }
  return c;
}

// One 32-feature output pair (mt even/odd) for FOUR batch row-tiles.
// Bias folded into the MFMA C operand. 8 independent MFMA chains; the two
// weight-tile streams (tb0/tb1) are each loaded once and reused 4x (CSE).
template <int KT, int TBASE, int PB>
__device__ __forceinline__ void ntp_pair(
    const _Float16* __restrict__ packs, const float* __restrict__ pl, int lane,
    int q, const Frag& a0, const Frag& a1, const Frag& a2, const Frag& a3,
    half8& r0, half8& r1, half8& r2, half8& r3) {
  const f32x4 bias0 = *(const f32x4*)(pl + PB + (q << 2));
  const f32x4 bias1 = *(const f32x4*)(pl + PB + 16 + (q << 2));
  const _Float16* tb0 = packs + (size_t)TBASE * TILE_HALVES + lane * 8;
  const _Float16* tb1 = tb0 + (size_t)KT * TILE_HALVES;
  const f32x4 c00 = chain<KT>(tb0, a0, bias0);
  const f32x4 c01 = chain<KT>(tb0, a1, bias0);
  const f32x4 c02 = chain<KT>(tb0, a2, bias0);
  const f32x4 c03 = chain<KT>(tb0, a3, bias0);
  const f32x4 c10 = chain<KT>(tb1, a0, bias1);
  const f32x4 c11 = chain<KT>(tb1, a1, bias1);
  const f32x4 c12 = chain<KT>(tb1, a2, bias1);
  const f32x4 c13 = chain<KT>(tb1, a3, bias1);
  // C-output at lane (m,q) = feats {32*ntp + 4q+j (even mt), +16 (odd mt)},
  // batch col m == exactly the B-fragment this lane feeds to the next layer
  // under the fixed K-permutation fi(q,j)=16*(j>>2)+4q+(j&3) baked into the
  // weight pack. Transition = in-register ReLU + f16 cvt. No LDS, no shuffle.
  r0 = relu_pack(c00, c10);
  r1 = relu_pack(c01, c11);
  r2 = relu_pack(c02, c12);
  r3 = relu_pack(c03, c13);
}

template <int FI, int FO, int LBASE, int PBIAS>
__device__ __forceinline__ void layerX(
    const _Float16* __restrict__ packs, const float* __restrict__ pl, int lane,
    int q, const Frag& a0, const Frag& a1, const Frag& a2, const Frag& a3,
    Frag& o0, Frag& o1, Frag& o2, Frag& o3) {
  constexpr int KT = FI / 32, NTP = FO / 32;
  ntp_pair<KT, LBASE + 0 * 2 * KT, PBIAS + 0 * 32>(
      packs, pl, lane, q, a0, a1, a2, a3, o0.k0, o1.k0, o2.k0, o3.k0);
  if constexpr (NTP > 1)
    ntp_pair<KT, LBASE + 1 * 2 * KT, PBIAS + 1 * 32>(
        packs, pl, lane, q, a0, a1, a2, a3, o0.k1, o1.k1, o2.k1, o3.k1);
  if constexpr (NTP > 2) {
    ntp_pair<KT, LBASE + 2 * 2 * KT, PBIAS + 2 * 32>(
        packs, pl, lane, q, a0, a1, a2, a3, o0.k2, o1.k2, o2.k2, o3.k2);
    ntp_pair<KT, LBASE + 3 * 2 * KT, PBIAS + 3 * 32>(
        packs, pl, lane, q, a0, a1, a2, a3, o0.k3, o1.k3, o2.k3, o3.k3);
  }
}

// grid (256 d, 2 batch-halves), 512 threads, 2 blocks/CU (R3/R5 structure).
// Phase 1: coalesced gather (R5). Phase 2: 2 iterations of 8 waves x 4
// row-tiles x 16 rows = 1024 rows, fully in-register between layers.
// R6 change: NO partial buffer / NO reduce kernel -- each block atomically
// adds its per-row sums (v + bias6) straight into out[] (float atomicAdd is
// device-scope on gfx950, correct across XCDs). out is zeroed by an 8 KB
// hipMemsetAsync before launch. Saves one dispatch + gap + 2 MB round-trip.
__global__ __launch_bounds__(512, 2) void mlp_fused(
    const float* __restrict__ x,
    const float* __restrict__ W0, const float* __restrict__ b0,
    const float* __restrict__ W1, const float* __restrict__ b1,
    const float* __restrict__ W2, const float* __restrict__ b2,
    const float* __restrict__ W3, const float* __restrict__ b3,
    const float* __restrict__ W4, const float* __restrict__ b4,
    const float* __restrict__ W5, const float* __restrict__ b5,
    const float* __restrict__ W6, const float* __restrict__ b6,
    float* __restrict__ out) {
  const int t = threadIdx.x;
  const int lane = t & 63;
  const int wave = t >> 6;
  const int m = lane & 15, q = lane >> 4;
  const int d = blockIdx.x;
  const int halfb = blockIdx.y;

  __shared__ __align__(16) _Float16 packs[NTILES * TILE_HALVES];  // 41 KB
  __shared__ __align__(16) float xs[1024];                        // 4 KB
  __shared__ __align__(16) float pl[P_TOT];

  // ---- phase 1a: stage x column (stride-1KB gather, issued all at once) ----
  for (int i = t; i < 1024; i += 512)
    xs[i] = x[(size_t)(halfb * 1024 + i) * DIM + d];

  // ---- phase 1b: gather W1..W5[d] into A-fragment order (f16 rne) ----
  // Target: packs[tile][jq*16+jm][j] =
  //   (f16) W[32*kt + 16*(j>>2) + 4*jq + (j&3)][16*mt + jm].
  // Job shape (R5): (tile, jq, jm4) covers jm = 4*jm4 .. +3 via 8 coalesced
  // float4 loads (rows {0..3,16..19} + 32kt+4jq; cols 16mt+4jm4..+3)
  // and 4 contiguous ds_write_b128.
  for (int job = t; job < NTILES * 16; job += 512) {
    const int tile = job >> 4, sub = job & 15;
    const int jq = sub >> 2, jm4 = sub & 3;
    const float* W; int FI, FO, lt;
    if (tile < 4)       { W = W1; FI = 32;  FO = 64;  lt = tile; }
    else if (tile < 20) { W = W2; FI = 64;  FO = 128; lt = tile - 4; }
    else if (tile < 36) { W = W3; FI = 128; FO = 64;  lt = tile - 20; }
    else if (tile < 40) { W = W4; FI = 64;  FO = 32;  lt = tile - 36; }
    else                { W = W5; FI = 32;  FO = 16;  lt = 0; }
    const int KT = FI >> 5;
    const int mt = lt / KT, kt = lt - mt * KT;
    const float* Wp = W + (size_t)d * FI * FO +
                      (size_t)(kt * 32 + 4 * jq) * FO + mt * 16 + jm4 * 4;
    const f32x4 v0 = *(const f32x4*)(Wp + (size_t)0 * FO);
    const f32x4 v1 = *(const f32x4*)(Wp + (size_t)1 * FO);
    const f32x4 v2 = *(const f32x4*)(Wp + (size_t)2 * FO);
    const f32x4 v3 = *(const f32x4*)(Wp + (size_t)3 * FO);
    const f32x4 v4 = *(const f32x4*)(Wp + (size_t)16 * FO);
    const f32x4 v5 = *(const f32x4*)(Wp + (size_t)17 * FO);
    const f32x4 v6 = *(const f32x4*)(Wp + (size_t)18 * FO);
    const f32x4 v7 = *(const f32x4*)(Wp + (size_t)19 * FO);
    _Float16* pb =
        packs + (size_t)tile * TILE_HALVES + (size_t)(jq * 16 + jm4 * 4) * 8;
#pragma unroll
    for (int c = 0; c < 4; ++c) {
      half8 h;
      h[0] = (_Float16)v0[c];
      h[1] = (_Float16)v1[c];
      h[2] = (_Float16)v2[c];
      h[3] = (_Float16)v3[c];
      h[4] = (_Float16)v4[c];
      h[5] = (_Float16)v5[c];
      h[6] = (_Float16)v6[c];
      h[7] = (_Float16)v7[c];
      *(half8*)(pb + c * 8) = h;
    }
  }
  // ---- phase 1c: stage small params (W0,b0,W6,b1..b5,b6) as f32 ----
  for (int i = t; i < P_TOT; i += 512) {
    float v;
    if (i < 32)       v = W0[d * 32 + i];
    else if (i < 64)  v = b0[d * 32 + i - 32];
    else if (i < 80)  v = W6[d * 16 + i - 64];
    else if (i < 144) v = b1[d * 64 + i - 80];
    else if (i < 272) v = b2[d * 128 + i - 144];
    else if (i < 336) v = b3[d * 64 + i - 272];
    else if (i < 368) v = b4[d * 32 + i - 336];
    else if (i < 384) v = b5[d * 16 + i - 368];
    else              v = b6[d];
    pl[i] = v;
  }

  __syncthreads();   // the ONLY barrier

  Frag pA0, pA1, pA2, pA3, pB0, pB1, pB2, pB3;  // ping-pong, named members

  for (int it = 0; it < 2; ++it) {
    // Compiler fence: keep the (cheap, loop-invariant) LDS reads of weights
    // and biases IN the loop -- hoisting all 41 weight tiles would need
    // 164+ VGPRs and re-trigger spill.
    asm volatile("" ::: "memory");

    const int row0 = halfb * 1024 + it * 512 + wave * 64;

    // L0/L6 params (permuted order for L0 so L1's B-frag is direct).
    const f32x4 w0a = *(const f32x4*)(pl + P_W0 + 4 * q);
    const f32x4 w0b = *(const f32x4*)(pl + P_W0 + 16 + 4 * q);
    const f32x4 b0a = *(const f32x4*)(pl + P_B0 + 4 * q);
    const f32x4 b0b = *(const f32x4*)(pl + P_B0 + 16 + 4 * q);

    // L0: 1 -> 32 in VALU, directly in permuted B-frag order.
    {
      const int xb = it * 512 + wave * 64 + m;
      const float xv0 = xs[xb];
      const float xv1 = xs[xb + 16];
      const float xv2 = xs[xb + 32];
      const float xv3 = xs[xb + 48];
      half8 h0, h1, h2, h3;
#pragma unroll
      for (int j = 0; j < 4; ++j) {
        h0[j]     = (_Float16)fmaxf(fmaf(xv0, w0a[j], b0a[j]), 0.0f);
        h0[4 + j] = (_Float16)fmaxf(fmaf(xv0, w0b[j], b0b[j]), 0.0f);
        h1[j]     = (_Float16)fmaxf(fmaf(xv1, w0a[j], b0a[j]), 0.0f);
        h1[4 + j] = (_Float16)fmaxf(fmaf(xv1, w0b[j], b0b[j]), 0.0f);
        h2[j]     = (_Float16)fmaxf(fmaf(xv2, w0a[j], b0a[j]), 0.0f);
        h2[4 + j] = (_Float16)fmaxf(fmaf(xv2, w0b[j], b0b[j]), 0.0f);
        h3[j]     = (_Float16)fmaxf(fmaf(xv3, w0a[j], b0a[j]), 0.0f);
        h3[4 + j] = (_Float16)fmaxf(fmaf(xv3, w0b[j], b0b[j]), 0.0f);
      }
      pA0.k0 = h0;
      pA1.k0 = h1;
      pA2.k0 = h2;
      pA3.k0 = h3;
    }

    layerX<32, 64, 0, P_B1>(packs, pl, lane, q,                    // L1
                            pA0, pA1, pA2, pA3, pB0, pB1, pB2, pB3);
    layerX<64, 128, 4, P_B2>(packs, pl, lane, q,                   // L2
                             pB0, pB1, pB2, pB3, pA0, pA1, pA2, pA3);
    layerX<128, 64, 20, P_B3>(packs, pl, lane, q,                  // L3
                              pA0, pA1, pA2, pA3, pB0, pB1, pB2, pB3);
    layerX<64, 32, 36, P_B4>(packs, pl, lane, q,                   // L4
                             pB0, pB1, pB2, pB3, pA0, pA1, pA2, pA3);

    // L5 (32->16, single tile) + L6 (16->1) fully in-register.
    const f32x4 bias5 = *(const f32x4*)(pl + P_B5 + 4 * q);
    const f32x4 w6v = *(const f32x4*)(pl + P_W6 + 4 * q);
    const float bias6 = pl[P_B6];
    const half8 wf5 =
        *(const half8*)(packs + (size_t)40 * TILE_HALVES + lane * 8);

    const f32x4 a50 = __builtin_amdgcn_mfma_f32_16x16x32_f16(
        wf5, pA0.k0, bias5, 0, 0, 0);
    const f32x4 a51 = __builtin_amdgcn_mfma_f32_16x16x32_f16(
        wf5, pA1.k0, bias5, 0, 0, 0);
    const f32x4 a52 = __builtin_amdgcn_mfma_f32_16x16x32_f16(
        wf5, pA2.k0, bias5, 0, 0, 0);
    const f32x4 a53 = __builtin_amdgcn_mfma_f32_16x16x32_f16(
        wf5, pA3.k0, bias5, 0, 0, 0);
    // lane (m,q) holds H5[4q+r][batch m]; dot with W6 then reduce over q.
    float v0 = 0.0f, v1 = 0.0f, v2 = 0.0f, v3 = 0.0f;
#pragma unroll
    for (int r = 0; r < 4; ++r) {
      v0 += fmaxf(a50[r], 0.0f) * w6v[r];
      v1 += fmaxf(a51[r], 0.0f) * w6v[r];
      v2 += fmaxf(a52[r], 0.0f) * w6v[r];
      v3 += fmaxf(a53[r], 0.0f) * w6v[r];
    }
    v0 += __shfl_xor(v0, 16);
    v0 += __shfl_xor(v0, 32);
    v1 += __shfl_xor(v1, 16);
    v1 += __shfl_xor(v1, 32);
    v2 += __shfl_xor(v2, 16);
    v2 += __shfl_xor(v2, 32);
    v3 += __shfl_xor(v3, 16);
    v3 += __shfl_xor(v3, 32);
    if (q == 0) {
      // Device-scope float atomics: direct cross-d accumulation into out.
      atomicAdd(&out[row0 + m],      v0 + bias6);
      atomicAdd(&out[row0 + 16 + m], v1 + bias6);
      atomicAdd(&out[row0 + 32 + m], v2 + bias6);
      atomicAdd(&out[row0 + 48 + m], v3 + bias6);
    }
  }
}

extern "C" void kernel_launch(void* const* d_in, const int* in_sizes, int n_in,
                              void* d_out, int out_size, void* d_ws, size_t ws_size,
                              hipStream_t stream) {
  const float* x = (const float*)d_in[0];
  const float* W[7];
  const float* B[7];
  for (int l = 0; l < 7; ++l) {
    W[l] = (const float*)d_in[1 + 2 * l];
    B[l] = (const float*)d_in[2 + 2 * l];
  }

  // Zero the 8 KB output, then accumulate into it atomically from all blocks.
  hipMemsetAsync(d_out, 0, out_size, stream);

  mlp_fused<<<dim3(DIM, 2), dim3(512), 0, stream>>>(
      x, W[0], B[0], W[1], B[1], W[2], B[2], W[3], B[3], W[4], B[4], W[5], B[5],
      W[6], B[6], (float*)d_out);
}